// Round 4
// baseline (265.174 us; speedup 1.0000x reference)
//
#include <hip/hip_runtime.h>
#include <hip/hip_bf16.h>
#include <stdint.h>

// B=32768 queries, M=4096 memory rows, D=128.
//   logits = Q @ M^T ; attn = softmax(logits) ; out = attn @ M
// Flash-style fused kernel. bf16x3-split MFMA QK^T (near-fp32), bf16 PV.
// v4: split-M (8-wave blocks, waves 0-3 -> tiles [0,64), waves 4-7 ->
// tiles [64,128), merge through LDS). Fix vs v3: register budget.
// v3's __launch_bounds__(512,2) capped VGPR at 128 -> ~350MB/dispatch of
// scratch spill traffic. Now amdgpu_waves_per_eu(2) -> 256 VGPR cap,
// ~200 live regs fit with 2 waves/SIMD and zero spill.

typedef float   f32x16 __attribute__((ext_vector_type(16)));
typedef short   bf16x8 __attribute__((ext_vector_type(8)));
typedef uint32_t u32;

#define AS1 __attribute__((address_space(1)))
#define AS3 __attribute__((address_space(3)))

#define D_DIM 128
#define TILE_HW 12288     // halfwords per 32-row tile: [khi 4096|klo 4096|v 4096]
#define HALF_TILES 64     // tiles per wave-group

#if __has_builtin(__builtin_amdgcn_exp2f)
#define EXP2F(x) __builtin_amdgcn_exp2f(x)
#else
#define EXP2F(x) exp2f(x)
#endif

__device__ __forceinline__ uint16_t f32_to_bf16_rne(float x) {
    u32 u = __float_as_uint(x);
    u32 r = u + 0x7fffu + ((u >> 16) & 1u);
    return (uint16_t)(r >> 16);
}
__device__ __forceinline__ float bf16_to_f32(uint16_t h) {
    return __uint_as_float(((u32)h) << 16);
}

// ---------------------------------------------------------------------------
// Prep: memory -> interleaved fragment-linear bf16 tiles in d_ws.
// Per tile mt (24576 B): [0,8K) khi frags, [8K,16K) klo frags, [16K,24K) v frags.
//   khi/klo frag kk: element = memory[mt*32 + (lane&31)][kk*16 + (lane>>5)*8 + e]
//   v frag f=ks*4+dt: element = memory[mt*32 + ks*16 + (lane>>5)*8 + e][dt*32 + (lane&31)]
// ---------------------------------------------------------------------------
__global__ void prep_frags(const float* __restrict__ mem,
                           uint16_t* __restrict__ kv) {
    int t = blockIdx.x * blockDim.x + threadIdx.x;  // 0..65535
    int lane = t & 63;
    int fi = t >> 6;                                // 0..1023
    int f8 = fi & 7, mt = fi >> 3;
    size_t base = (size_t)mt * TILE_HW;
    {   // K fragment (hi/lo split)
        int m  = mt * 32 + (lane & 31);
        int d0 = f8 * 16 + (lane >> 5) * 8;
        const float* src = mem + (size_t)m * D_DIM + d0;
        #pragma unroll
        for (int e = 0; e < 8; ++e) {
            float x = src[e];
            uint16_t hb = f32_to_bf16_rne(x);
            kv[base + f8 * 512 + lane * 8 + e] = hb;
            kv[base + 4096 + f8 * 512 + lane * 8 + e] =
                f32_to_bf16_rne(x - bf16_to_f32(hb));
        }
    }
    {   // V^T fragment (plain bf16)
        int dt = fi & 3, ks = (fi >> 2) & 1;
        int d  = dt * 32 + (lane & 31);
        int m0 = mt * 32 + ks * 16 + (lane >> 5) * 8;
        #pragma unroll
        for (int e = 0; e < 8; ++e)
            kv[base + 8192 + f8 * 512 + lane * 8 + e] =
                f32_to_bf16_rne(mem[(size_t)(m0 + e) * D_DIM + d]);
    }
}

// ---------------------------------------------------------------------------
// Main kernel: 256 blocks x 512 threads (8 waves, 2/SIMD).
// Wave group grp = wave>>2 handles tiles [grp*64, grp*64+64).
// LDS: sbuf[grp][cur] double-buffered 24KB tiles (96 KB total).
// ---------------------------------------------------------------------------

#define STAGE(t_, wb_) do {                                                   \
    const char* g_ = (const char*)(kv + (size_t)(tilebase + (t_)) * TILE_HW); \
    char* l_ = (char*)&sbuf[grp][wb_][0];                                     \
    _Pragma("unroll")                                                         \
    for (int j_ = 0; j_ < 6; ++j_) {                                          \
        int ch_ = wsub * 6 + j_;                                              \
        __builtin_amdgcn_global_load_lds(                                     \
            (const AS1 char*)(g_ + ch_ * 1024 + lane * 16),                   \
            (AS3 char*)(l_ + ch_ * 1024), 16, 0, 0);                          \
    }                                                                         \
} while (0)

#define READ_KV(rb_, vf_) do {                                                \
    const uint16_t* b_ = &sbuf[grp][rb_][0] + lane * 8;                       \
    _Pragma("unroll")                                                         \
    for (int kk_ = 0; kk_ < 8; ++kk_) {                                       \
        kh[kk_]  = *(const bf16x8*)(b_ + kk_ * 512);                          \
        kl[kk_]  = *(const bf16x8*)(b_ + 4096 + kk_ * 512);                   \
        vf_[kk_] = *(const bf16x8*)(b_ + 8192 + kk_ * 512);                   \
    }                                                                         \
} while (0)

// Declares s0_,s1_,s2_ in enclosing scope; issues 24 MFMAs for tile's QK^T.
#define QK_ISSUE()                                                            \
    f32x16 s0_, s1_, s2_;                                                     \
    _Pragma("unroll")                                                         \
    for (int i_ = 0; i_ < 16; ++i_) { s0_[i_]=0.f; s1_[i_]=0.f; s2_[i_]=0.f; }\
    _Pragma("unroll")                                                         \
    for (int kk_ = 0; kk_ < 8; ++kk_) {                                       \
        s0_ = __builtin_amdgcn_mfma_f32_32x32x16_bf16(kh[kk_], qhi[kk_], s0_, 0, 0, 0); \
        s1_ = __builtin_amdgcn_mfma_f32_32x32x16_bf16(kh[kk_], qlo[kk_], s1_, 0, 0, 0); \
        s2_ = __builtin_amdgcn_mfma_f32_32x32x16_bf16(kl[kk_], qhi[kk_], s2_, 0, 0, 0); \
    }

// Online softmax on sC_ (summed log2-logits, Sᵀ layout: q=lane&31) + PV MFMAs.
#define SOFTMAX_PV(sC_, vfC_) do {                                            \
    float a0_=fmaxf(sC_[0],sC_[1]),  a1_=fmaxf(sC_[2],sC_[3]);                \
    float a2_=fmaxf(sC_[4],sC_[5]),  a3_=fmaxf(sC_[6],sC_[7]);                \
    float a4_=fmaxf(sC_[8],sC_[9]),  a5_=fmaxf(sC_[10],sC_[11]);              \
    float a6_=fmaxf(sC_[12],sC_[13]),a7_=fmaxf(sC_[14],sC_[15]);              \
    float b0_=fmaxf(a0_,a1_), b1_=fmaxf(a2_,a3_);                             \
    float b2_=fmaxf(a4_,a5_), b3_=fmaxf(a6_,a7_);                             \
    float tmax_ = fmaxf(fmaxf(b0_,b1_), fmaxf(b2_,b3_));                      \
    tmax_ = fmaxf(tmax_, __shfl_xor(tmax_, 32));                              \
    if (__any(tmax_ > m_run + 8.0f)) {     /* defer-max (T13) */              \
        float mn_ = fmaxf(m_run, tmax_);                                      \
        float fr_ = EXP2F(m_run - mn_);                                       \
        m_run = mn_; l_run *= fr_;                                            \
        _Pragma("unroll")                                                     \
        for (int r_ = 0; r_ < 16; ++r_) {                                     \
            O0[r_] *= fr_; O1[r_] *= fr_; O2[r_] *= fr_; O3[r_] *= fr_;       \
        }                                                                     \
    }                                                                         \
    float p_[16];                                                             \
    _Pragma("unroll")                                                         \
    for (int r_ = 0; r_ < 16; ++r_) p_[r_] = EXP2F(sC_[r_] - m_run);          \
    { float q0_=p_[0]+p_[1],  q1_=p_[2]+p_[3],  q2_=p_[4]+p_[5],  q3_=p_[6]+p_[7];   \
      float q4_=p_[8]+p_[9],  q5_=p_[10]+p_[11],q6_=p_[12]+p_[13],q7_=p_[14]+p_[15]; \
      l_run += ((q0_+q1_)+(q2_+q3_)) + ((q4_+q5_)+(q6_+q7_)); }               \
    u32 c_[8];                                                                \
    _Pragma("unroll")                                                         \
    for (int j_ = 0; j_ < 8; ++j_)                                            \
        asm("v_cvt_pk_bf16_f32 %0, %1, %2"                                    \
            : "=v"(c_[j_]) : "v"(p_[2*j_]), "v"(p_[2*j_+1]));                 \
    asm("v_permlane32_swap_b32 %0, %1" : "+v"(c_[0]), "+v"(c_[2]));           \
    asm("v_permlane32_swap_b32 %0, %1" : "+v"(c_[1]), "+v"(c_[3]));           \
    asm("v_permlane32_swap_b32 %0, %1" : "+v"(c_[4]), "+v"(c_[6]));           \
    asm("v_permlane32_swap_b32 %0, %1" : "+v"(c_[5]), "+v"(c_[7]));           \
    bf16x8 pf0_, pf1_;                                                        \
    { u32 w_[4] = {c_[0], c_[1], c_[2], c_[3]}; __builtin_memcpy(&pf0_, w_, 16); } \
    { u32 w_[4] = {c_[4], c_[5], c_[6], c_[7]}; __builtin_memcpy(&pf1_, w_, 16); } \
    O0 = __builtin_amdgcn_mfma_f32_32x32x16_bf16(vfC_[0], pf0_, O0, 0, 0, 0); \
    O1 = __builtin_amdgcn_mfma_f32_32x32x16_bf16(vfC_[1], pf0_, O1, 0, 0, 0); \
    O2 = __builtin_amdgcn_mfma_f32_32x32x16_bf16(vfC_[2], pf0_, O2, 0, 0, 0); \
    O3 = __builtin_amdgcn_mfma_f32_32x32x16_bf16(vfC_[3], pf0_, O3, 0, 0, 0); \
    O0 = __builtin_amdgcn_mfma_f32_32x32x16_bf16(vfC_[4], pf1_, O0, 0, 0, 0); \
    O1 = __builtin_amdgcn_mfma_f32_32x32x16_bf16(vfC_[5], pf1_, O1, 0, 0, 0); \
    O2 = __builtin_amdgcn_mfma_f32_32x32x16_bf16(vfC_[6], pf1_, O2, 0, 0, 0); \
    O3 = __builtin_amdgcn_mfma_f32_32x32x16_bf16(vfC_[7], pf1_, O3, 0, 0, 0); \
} while (0)

// One pipeline stage: read tile tn_ frags, stage tile tn_+1, issue QK(tn_)
// (fills MFMA pipe), softmax+PV of tile tn_-1 (VALU overlaps), sum scores.
#define HALF(tn_, rb_, sCur_, sNxt_, vfCur_, vfNxt_, doStage_) do {           \
    READ_KV(rb_, vfNxt_);                                                     \
    if (doStage_) STAGE((tn_) + 1, (rb_) ^ 1);                                \
    QK_ISSUE();                                                               \
    SOFTMAX_PV(sCur_, vfCur_);                                                \
    sNxt_ = s0_ + s1_ + s2_;                                                  \
    __syncthreads();                                                          \
} while (0)

// Epilogue exchange region per wave-pair wsub: 4224 floats
// [0,4096): O as float4 per (t,gq,lane); [4096,4160): m; [4160,4224): l.
#define XWRITE(Ot_, t_) do {                                                  \
    _Pragma("unroll")                                                         \
    for (int g_ = 0; g_ < 4; ++g_) {                                          \
        float4 v_ = { Ot_[4*g_+0], Ot_[4*g_+1], Ot_[4*g_+2], Ot_[4*g_+3] };   \
        *(float4*)(reg + ((t_)*4 + g_) * 256 + lane * 4) = v_;                \
    }                                                                         \
} while (0)

#define XCOMB_STORE(Ot_, t_) do {                                             \
    _Pragma("unroll")                                                         \
    for (int g_ = 0; g_ < 4; ++g_) {                                          \
        float4 p_ = *(const float4*)(reg + ((t_)*4 + g_) * 256 + lane * 4);   \
        float4 v_;                                                            \
        v_.x = (Ot_[4*g_+0] * a_c + p_.x * b_c) * rinv;                       \
        v_.y = (Ot_[4*g_+1] * a_c + p_.y * b_c) * rinv;                       \
        v_.z = (Ot_[4*g_+2] * a_c + p_.z * b_c) * rinv;                       \
        v_.w = (Ot_[4*g_+3] * a_c + p_.w * b_c) * rinv;                       \
        int d_ = (t_) * 32 + 8 * g_ + 4 * hi32;                               \
        *(float4*)(out + (size_t)qrow * D_DIM + d_) = v_;                     \
    }                                                                         \
} while (0)

__global__ __launch_bounds__(512)
__attribute__((amdgpu_waves_per_eu(2)))
void attn_main(const float* __restrict__ qin,
               const uint16_t* __restrict__ kv,
               float* __restrict__ out) {
    __shared__ uint16_t sbuf[2][2][TILE_HW];   // [grp][cur], 96 KB

    const int lane = threadIdx.x & 63;
    const int wave = threadIdx.x >> 6;
    const int grp  = wave >> 2;        // 0: tiles 0-63, 1: tiles 64-127
    const int wsub = wave & 3;
    const int tilebase = grp * HALF_TILES;
    const int q0   = blockIdx.x * 128 + wsub * 32;
    const int qrow = q0 + (lane & 31);
    const int hi32 = lane >> 5;

    // Q prep: scale by log2(e), split into bf16 hi/lo (B-frag of Sᵀ MFMA).
    bf16x8 qhi[8], qlo[8];
    {
        const float LOG2E = 1.44269504088896340736f;
        #pragma unroll
        for (int kk = 0; kk < 8; ++kk) {
            const float* src = qin + (size_t)qrow * D_DIM + kk * 16 + hi32 * 8;
            float4 a = *(const float4*)(src);
            float4 b = *(const float4*)(src + 4);
            float xs[8] = {a.x, a.y, a.z, a.w, b.x, b.y, b.z, b.w};
            #pragma unroll
            for (int e = 0; e < 8; ++e) {
                float x = xs[e] * LOG2E;
                uint16_t hb = f32_to_bf16_rne(x);
                qhi[kk][e] = (short)hb;
                qlo[kk][e] = (short)f32_to_bf16_rne(x - bf16_to_f32(hb));
            }
        }
    }

    f32x16 O0, O1, O2, O3;
    #pragma unroll
    for (int i = 0; i < 16; ++i) { O0[i]=0.f; O1[i]=0.f; O2[i]=0.f; O3[i]=0.f; }
    float m_run = -1e30f, l_run = 0.f;

    bf16x8 kh[8], kl[8], vfA[8], vfB[8];
    f32x16 sA, sB;

    // Pipeline prologue: stage(0), QK(0) -> sA, stage(1).
    STAGE(0, 0);
    __syncthreads();
    READ_KV(0, vfA);
    STAGE(1, 1);
    {
        QK_ISSUE();
        sA = s0_ + s1_ + s2_;
    }
    __syncthreads();

    // Steady state: halves tn = 1..62 in pairs, then tn = 63 (no stage).
    #pragma unroll 1
    for (int tp = 0; tp < 31; ++tp) {
        const int tn = 2 * tp + 1;
        HALF(tn,     1, sA, sB, vfA, vfB, true);
        HALF(tn + 1, 0, sB, sA, vfB, vfA, true);
    }
    HALF(63, 1, sA, sB, vfA, vfB, false);
    // Drain: softmax + PV for last tile.
    SOFTMAX_PV(sB, vfB);

    // ---- split-M merge ----
    l_run += __shfl_xor(l_run, 32);     // pair-lane partial sums
    __syncthreads();
    float* xch = (float*)&sbuf[0][0][0];
    float* reg = xch + wsub * 4224;
    if (grp == 1) {
        XWRITE(O0, 0); XWRITE(O1, 1); XWRITE(O2, 2); XWRITE(O3, 3);
        reg[4096 + lane] = m_run;
        reg[4160 + lane] = l_run;
    }
    __syncthreads();
    if (grp == 0) {
        float m_p = reg[4096 + lane];
        float l_p = reg[4160 + lane];
        float mn  = fmaxf(m_run, m_p);
        float a_c = EXP2F(m_run - mn);
        float b_c = EXP2F(m_p - mn);
        float rinv = 1.0f / (l_run * a_c + l_p * b_c);
        XCOMB_STORE(O0, 0); XCOMB_STORE(O1, 1);
        XCOMB_STORE(O2, 2); XCOMB_STORE(O3, 3);
    }
}

extern "C" void kernel_launch(void* const* d_in, const int* in_sizes, int n_in,
                              void* d_out, int out_size, void* d_ws, size_t ws_size,
                              hipStream_t stream) {
    const float* local_stats = (const float*)d_in[0];   // [32768,128] f32
    const float* memory      = (const float*)d_in[1];   // [4096,128]  f32
    float* out = (float*)d_out;                         // [32768,128] f32

    uint16_t* kv = (uint16_t*)d_ws;   // 128 tiles x 24576 B = 3 MB

    prep_frags<<<256, 256, 0, stream>>>(memory, kv);
    attn_main<<<256, 512, 0, stream>>>(local_stats, kv, out);
}

// Round 5
// 176.505 us; speedup vs baseline: 1.5024x; 1.5024x over previous
//
#include <hip/hip_runtime.h>
#include <hip/hip_bf16.h>
#include <stdint.h>

// B=32768 queries, M=4096 memory rows, D=128.
//   logits = Q @ M^T ; attn = softmax(logits) ; out = attn @ M
// Flash-style fused kernel. bf16x3-split MFMA QK^T (near-fp32), bf16 PV.
// v5: flash-decoding split-M ACROSS BLOCKS. Round-2 block structure
// (256 thr, 4 waves, 196 VGPR, 48KB LDS — no spill) x 512 blocks:
// block bx does q-chunk bx>>1, memory half bx&1 (64 tiles), writes
// partial (O,m,l) to ws; a light merge kernel combines the halves.
// 2 blocks/CU -> 2 waves/SIMD; independent blocks hide each other's
// barrier/dep stalls. (v3/v4's 512-thread workgroup was stuck at a
// 128-VGPR allocation -> 300MB scratch spill; this avoids it.)

typedef float   f32x16 __attribute__((ext_vector_type(16)));
typedef short   bf16x8 __attribute__((ext_vector_type(8)));
typedef uint32_t u32;

#define AS1 __attribute__((address_space(1)))
#define AS3 __attribute__((address_space(3)))

#define D_DIM 128
#define B_ROWS 32768
#define TILE_HW 12288     // halfwords per 32-row tile: [khi 4096|klo 4096|v 4096]
#define HALF_TILES 64     // tiles per block

#if __has_builtin(__builtin_amdgcn_exp2f)
#define EXP2F(x) __builtin_amdgcn_exp2f(x)
#else
#define EXP2F(x) exp2f(x)
#endif

__device__ __forceinline__ uint16_t f32_to_bf16_rne(float x) {
    u32 u = __float_as_uint(x);
    u32 r = u + 0x7fffu + ((u >> 16) & 1u);
    return (uint16_t)(r >> 16);
}
__device__ __forceinline__ float bf16_to_f32(uint16_t h) {
    return __uint_as_float(((u32)h) << 16);
}

// ---------------------------------------------------------------------------
// Prep: memory -> interleaved fragment-linear bf16 tiles in d_ws.
// Per tile mt (24576 B): [0,8K) khi frags, [8K,16K) klo frags, [16K,24K) v frags.
// ---------------------------------------------------------------------------
__global__ void prep_frags(const float* __restrict__ mem,
                           uint16_t* __restrict__ kv) {
    int t = blockIdx.x * blockDim.x + threadIdx.x;  // 0..65535
    int lane = t & 63;
    int fi = t >> 6;                                // 0..1023
    int f8 = fi & 7, mt = fi >> 3;
    size_t base = (size_t)mt * TILE_HW;
    {   // K fragment (hi/lo split)
        int m  = mt * 32 + (lane & 31);
        int d0 = f8 * 16 + (lane >> 5) * 8;
        const float* src = mem + (size_t)m * D_DIM + d0;
        #pragma unroll
        for (int e = 0; e < 8; ++e) {
            float x = src[e];
            uint16_t hb = f32_to_bf16_rne(x);
            kv[base + f8 * 512 + lane * 8 + e] = hb;
            kv[base + 4096 + f8 * 512 + lane * 8 + e] =
                f32_to_bf16_rne(x - bf16_to_f32(hb));
        }
    }
    {   // V^T fragment (plain bf16)
        int dt = fi & 3, ks = (fi >> 2) & 1;
        int d  = dt * 32 + (lane & 31);
        int m0 = mt * 32 + ks * 16 + (lane >> 5) * 8;
        #pragma unroll
        for (int e = 0; e < 8; ++e)
            kv[base + 8192 + f8 * 512 + lane * 8 + e] =
                f32_to_bf16_rne(mem[(size_t)(m0 + e) * D_DIM + d]);
    }
}

// ---------------------------------------------------------------------------
// Main kernel: 512 blocks x 256 threads (4 waves). Each wave: 32 q-rows,
// 64 memory tiles. LDS double-buffered 24KB tiles (48 KB).
// ---------------------------------------------------------------------------

#define STAGE(t_, wb_) do {                                                   \
    const char* g_ = (const char*)(kv + (size_t)(tilebase + (t_)) * TILE_HW); \
    char* l_ = (char*)&sbuf[wb_][0];                                          \
    _Pragma("unroll")                                                         \
    for (int j_ = 0; j_ < 6; ++j_) {                                          \
        int ch_ = wave * 6 + j_;                                              \
        __builtin_amdgcn_global_load_lds(                                     \
            (const AS1 char*)(g_ + ch_ * 1024 + lane * 16),                   \
            (AS3 char*)(l_ + ch_ * 1024), 16, 0, 0);                          \
    }                                                                         \
} while (0)

#define READ_KV(rb_, vf_) do {                                                \
    const uint16_t* b_ = &sbuf[rb_][0] + lane * 8;                            \
    _Pragma("unroll")                                                         \
    for (int kk_ = 0; kk_ < 8; ++kk_) {                                       \
        kh[kk_]  = *(const bf16x8*)(b_ + kk_ * 512);                          \
        kl[kk_]  = *(const bf16x8*)(b_ + 4096 + kk_ * 512);                   \
        vf_[kk_] = *(const bf16x8*)(b_ + 8192 + kk_ * 512);                   \
    }                                                                         \
} while (0)

// Declares s0_,s1_,s2_ in enclosing scope; issues 24 MFMAs for tile's QK^T.
#define QK_ISSUE()                                                            \
    f32x16 s0_, s1_, s2_;                                                     \
    _Pragma("unroll")                                                         \
    for (int i_ = 0; i_ < 16; ++i_) { s0_[i_]=0.f; s1_[i_]=0.f; s2_[i_]=0.f; }\
    _Pragma("unroll")                                                         \
    for (int kk_ = 0; kk_ < 8; ++kk_) {                                       \
        s0_ = __builtin_amdgcn_mfma_f32_32x32x16_bf16(kh[kk_], qhi[kk_], s0_, 0, 0, 0); \
        s1_ = __builtin_amdgcn_mfma_f32_32x32x16_bf16(kh[kk_], qlo[kk_], s1_, 0, 0, 0); \
        s2_ = __builtin_amdgcn_mfma_f32_32x32x16_bf16(kl[kk_], qhi[kk_], s2_, 0, 0, 0); \
    }

// Online softmax on sC_ (summed log2-logits, Sᵀ layout: q=lane&31) + PV MFMAs.
#define SOFTMAX_PV(sC_, vfC_) do {                                            \
    float a0_=fmaxf(sC_[0],sC_[1]),  a1_=fmaxf(sC_[2],sC_[3]);                \
    float a2_=fmaxf(sC_[4],sC_[5]),  a3_=fmaxf(sC_[6],sC_[7]);                \
    float a4_=fmaxf(sC_[8],sC_[9]),  a5_=fmaxf(sC_[10],sC_[11]);              \
    float a6_=fmaxf(sC_[12],sC_[13]),a7_=fmaxf(sC_[14],sC_[15]);              \
    float b0_=fmaxf(a0_,a1_), b1_=fmaxf(a2_,a3_);                             \
    float b2_=fmaxf(a4_,a5_), b3_=fmaxf(a6_,a7_);                             \
    float tmax_ = fmaxf(fmaxf(b0_,b1_), fmaxf(b2_,b3_));                      \
    tmax_ = fmaxf(tmax_, __shfl_xor(tmax_, 32));                              \
    if (__any(tmax_ > m_run + 8.0f)) {     /* defer-max (T13) */              \
        float mn_ = fmaxf(m_run, tmax_);                                      \
        float fr_ = EXP2F(m_run - mn_);                                       \
        m_run = mn_; l_run *= fr_;                                            \
        _Pragma("unroll")                                                     \
        for (int r_ = 0; r_ < 16; ++r_) {                                     \
            O0[r_] *= fr_; O1[r_] *= fr_; O2[r_] *= fr_; O3[r_] *= fr_;       \
        }                                                                     \
    }                                                                         \
    float p_[16];                                                             \
    _Pragma("unroll")                                                         \
    for (int r_ = 0; r_ < 16; ++r_) p_[r_] = EXP2F(sC_[r_] - m_run);          \
    { float q0_=p_[0]+p_[1],  q1_=p_[2]+p_[3],  q2_=p_[4]+p_[5],  q3_=p_[6]+p_[7];   \
      float q4_=p_[8]+p_[9],  q5_=p_[10]+p_[11],q6_=p_[12]+p_[13],q7_=p_[14]+p_[15]; \
      l_run += ((q0_+q1_)+(q2_+q3_)) + ((q4_+q5_)+(q6_+q7_)); }               \
    u32 c_[8];                                                                \
    _Pragma("unroll")                                                         \
    for (int j_ = 0; j_ < 8; ++j_)                                            \
        asm("v_cvt_pk_bf16_f32 %0, %1, %2"                                    \
            : "=v"(c_[j_]) : "v"(p_[2*j_]), "v"(p_[2*j_+1]));                 \
    asm("v_permlane32_swap_b32 %0, %1" : "+v"(c_[0]), "+v"(c_[2]));           \
    asm("v_permlane32_swap_b32 %0, %1" : "+v"(c_[1]), "+v"(c_[3]));           \
    asm("v_permlane32_swap_b32 %0, %1" : "+v"(c_[4]), "+v"(c_[6]));           \
    asm("v_permlane32_swap_b32 %0, %1" : "+v"(c_[5]), "+v"(c_[7]));           \
    bf16x8 pf0_, pf1_;                                                        \
    { u32 w_[4] = {c_[0], c_[1], c_[2], c_[3]}; __builtin_memcpy(&pf0_, w_, 16); } \
    { u32 w_[4] = {c_[4], c_[5], c_[6], c_[7]}; __builtin_memcpy(&pf1_, w_, 16); } \
    O0 = __builtin_amdgcn_mfma_f32_32x32x16_bf16(vfC_[0], pf0_, O0, 0, 0, 0); \
    O1 = __builtin_amdgcn_mfma_f32_32x32x16_bf16(vfC_[1], pf0_, O1, 0, 0, 0); \
    O2 = __builtin_amdgcn_mfma_f32_32x32x16_bf16(vfC_[2], pf0_, O2, 0, 0, 0); \
    O3 = __builtin_amdgcn_mfma_f32_32x32x16_bf16(vfC_[3], pf0_, O3, 0, 0, 0); \
    O0 = __builtin_amdgcn_mfma_f32_32x32x16_bf16(vfC_[4], pf1_, O0, 0, 0, 0); \
    O1 = __builtin_amdgcn_mfma_f32_32x32x16_bf16(vfC_[5], pf1_, O1, 0, 0, 0); \
    O2 = __builtin_amdgcn_mfma_f32_32x32x16_bf16(vfC_[6], pf1_, O2, 0, 0, 0); \
    O3 = __builtin_amdgcn_mfma_f32_32x32x16_bf16(vfC_[7], pf1_, O3, 0, 0, 0); \
} while (0)

// One pipeline stage: read tile tn_ frags, stage tile tn_+1, issue QK(tn_)
// (fills MFMA pipe), softmax+PV of tile tn_-1 (VALU overlaps), sum scores.
#define HALF(tn_, rb_, sCur_, sNxt_, vfCur_, vfNxt_, doStage_) do {           \
    READ_KV(rb_, vfNxt_);                                                     \
    if (doStage_) STAGE((tn_) + 1, (rb_) ^ 1);                                \
    QK_ISSUE();                                                               \
    SOFTMAX_PV(sCur_, vfCur_);                                                \
    sNxt_ = s0_ + s1_ + s2_;                                                  \
    __syncthreads();                                                          \
} while (0)

#define PSTORE_TILE(Ot_, t_) do {                                             \
    _Pragma("unroll")                                                         \
    for (int g_ = 0; g_ < 4; ++g_) {                                          \
        float4 v_ = { Ot_[4*g_+0], Ot_[4*g_+1], Ot_[4*g_+2], Ot_[4*g_+3] };   \
        int d_ = (t_) * 32 + 8 * g_ + 4 * hi32;                               \
        *(float4*)(prow + d_) = v_;                                           \
    }                                                                         \
} while (0)

__global__ __launch_bounds__(256, 1)
void attn_main(const float* __restrict__ qin,
               const uint16_t* __restrict__ kv,
               float* __restrict__ pout,      // [2][B_ROWS][128] partial O
               float2* __restrict__ pml) {    // [2][B_ROWS] (m, l)
    __shared__ uint16_t sbuf[2][TILE_HW];   // 2 x 24 KB

    const int lane = threadIdx.x & 63;
    const int wave = threadIdx.x >> 6;
    const int half = blockIdx.x & 1;
    const int tilebase = half * HALF_TILES;
    const int q0   = (blockIdx.x >> 1) * 128 + wave * 32;
    const int qrow = q0 + (lane & 31);
    const int hi32 = lane >> 5;

    // Q prep: scale by log2(e), split into bf16 hi/lo (B-frag of Sᵀ MFMA).
    bf16x8 qhi[8], qlo[8];
    {
        const float LOG2E = 1.44269504088896340736f;
        #pragma unroll
        for (int kk = 0; kk < 8; ++kk) {
            const float* src = qin + (size_t)qrow * D_DIM + kk * 16 + hi32 * 8;
            float4 a = *(const float4*)(src);
            float4 b = *(const float4*)(src + 4);
            float xs[8] = {a.x, a.y, a.z, a.w, b.x, b.y, b.z, b.w};
            #pragma unroll
            for (int e = 0; e < 8; ++e) {
                float x = xs[e] * LOG2E;
                uint16_t hb = f32_to_bf16_rne(x);
                qhi[kk][e] = (short)hb;
                qlo[kk][e] = (short)f32_to_bf16_rne(x - bf16_to_f32(hb));
            }
        }
    }

    f32x16 O0, O1, O2, O3;
    #pragma unroll
    for (int i = 0; i < 16; ++i) { O0[i]=0.f; O1[i]=0.f; O2[i]=0.f; O3[i]=0.f; }
    float m_run = -1e30f, l_run = 0.f;

    bf16x8 kh[8], kl[8], vfA[8], vfB[8];
    f32x16 sA, sB;

    // Pipeline prologue: stage(0), QK(0) -> sA, stage(1).
    STAGE(0, 0);
    __syncthreads();
    READ_KV(0, vfA);
    STAGE(1, 1);
    {
        QK_ISSUE();
        sA = s0_ + s1_ + s2_;
    }
    __syncthreads();

    // Steady state: halves tn = 1..62 in pairs, then tn = 63 (no stage).
    #pragma unroll 1
    for (int tp = 0; tp < 31; ++tp) {
        const int tn = 2 * tp + 1;
        HALF(tn,     1, sA, sB, vfA, vfB, true);
        HALF(tn + 1, 0, sB, sA, vfB, vfA, true);
    }
    HALF(63, 1, sA, sB, vfA, vfB, false);
    // Drain: softmax + PV for last tile.
    SOFTMAX_PV(sB, vfB);

    // ---- partial store (un-normalized O, plus m,l) ----
    l_run += __shfl_xor(l_run, 32);     // pair-lane partial sums
    float* prow = pout + ((size_t)half * B_ROWS + qrow) * D_DIM;
    PSTORE_TILE(O0, 0); PSTORE_TILE(O1, 1);
    PSTORE_TILE(O2, 2); PSTORE_TILE(O3, 3);
    if (lane < 32) {
        pml[(size_t)half * B_ROWS + qrow] = make_float2(m_run, l_run);
    }
}

// ---------------------------------------------------------------------------
// Merge: out = (P0*w0 + P1*w1) / (l0*w0 + l1*w1), w_i = exp2(m_i - max).
// One float4 per thread: 32768*32 float4s / 256 = 4096 blocks.
// ---------------------------------------------------------------------------
__global__ __launch_bounds__(256)
void merge_halves(const float* __restrict__ pout,
                  const float2* __restrict__ pml,
                  float* __restrict__ out) {
    int idx  = blockIdx.x * 256 + threadIdx.x;   // 0 .. 2^20-1
    int row  = idx >> 5;
    int c4   = idx & 31;
    float2 a = pml[row];
    float2 b = pml[B_ROWS + row];
    float mn = fmaxf(a.x, b.x);
    float wa = EXP2F(a.x - mn);
    float wb = EXP2F(b.x - mn);
    float rinv = 1.0f / (a.y * wa + b.y * wb);
    const float4* P0 = (const float4*)(pout + (size_t)row * D_DIM) + c4;
    const float4* P1 = (const float4*)(pout + ((size_t)B_ROWS + row) * D_DIM) + c4;
    float4 p0 = *P0, p1 = *P1;
    float4 v;
    v.x = (p0.x * wa + p1.x * wb) * rinv;
    v.y = (p0.y * wa + p1.y * wb) * rinv;
    v.z = (p0.z * wa + p1.z * wb) * rinv;
    v.w = (p0.w * wa + p1.w * wb) * rinv;
    *((float4*)(out + (size_t)row * D_DIM) + c4) = v;
}

extern "C" void kernel_launch(void* const* d_in, const int* in_sizes, int n_in,
                              void* d_out, int out_size, void* d_ws, size_t ws_size,
                              hipStream_t stream) {
    const float* local_stats = (const float*)d_in[0];   // [32768,128] f32
    const float* memory      = (const float*)d_in[1];   // [4096,128]  f32
    float* out = (float*)d_out;                         // [32768,128] f32

    // ws layout: kv frags 3MB | partial O 32MB | partial (m,l) 0.5MB
    uint16_t* kv  = (uint16_t*)d_ws;
    float*   pout = (float*)((char*)d_ws + 3 * 1024 * 1024);
    float2*  pml  = (float2*)((char*)pout + (size_t)2 * B_ROWS * D_DIM * 4);

    prep_frags<<<256, 256, 0, stream>>>(memory, kv);
    attn_main<<<512, 256, 0, stream>>>(local_stats, kv, pout, pml);
    merge_halves<<<4096, 256, 0, stream>>>(pout, pml, out);
}

// Round 6
// 151.068 us; speedup vs baseline: 1.7553x; 1.1684x over previous
//
#include <hip/hip_runtime.h>
#include <hip/hip_bf16.h>
#include <stdint.h>

// B=32768 queries, M=4096 memory rows, D=128.
//   logits = Q @ M^T ; attn = softmax(logits) ; out = attn @ M
// Flash-style fused kernel. bf16x3-split MFMA QK^T (near-fp32), bf16 PV.
// v6: register-budget fix so 2 blocks/CU actually co-reside.
// v5 held ~300 live regs/wave (unified VGPR+AGPR) -> only 1 block/CU
// resident (occupancy 11%), blocks serialized. Now: merged low-order QK
// chain, no cross-tile S pipeline, K/V fragments streamed from LDS ->
// ~220 regs, __launch_bounds__(256,2) => 2 waves/SIMD; TLP hides the
// dep-chain/barrier stalls that the dropped ILP used to cover.

typedef float   f32x16 __attribute__((ext_vector_type(16)));
typedef short   bf16x8 __attribute__((ext_vector_type(8)));
typedef uint32_t u32;

#define AS1 __attribute__((address_space(1)))
#define AS3 __attribute__((address_space(3)))

#define D_DIM 128
#define B_ROWS 32768
#define TILE_HW 12288     // halfwords per 32-row tile: [khi 4096|klo 4096|v 4096]
#define HALF_TILES 64     // tiles per block

#if __has_builtin(__builtin_amdgcn_exp2f)
#define EXP2F(x) __builtin_amdgcn_exp2f(x)
#else
#define EXP2F(x) exp2f(x)
#endif

__device__ __forceinline__ uint16_t f32_to_bf16_rne(float x) {
    u32 u = __float_as_uint(x);
    u32 r = u + 0x7fffu + ((u >> 16) & 1u);
    return (uint16_t)(r >> 16);
}
__device__ __forceinline__ float bf16_to_f32(uint16_t h) {
    return __uint_as_float(((u32)h) << 16);
}

// ---------------------------------------------------------------------------
// Prep: memory -> interleaved fragment-linear bf16 tiles in d_ws.
// Per tile mt (24576 B): [0,8K) khi frags, [8K,16K) klo frags, [16K,24K) v frags.
// ---------------------------------------------------------------------------
__global__ void prep_frags(const float* __restrict__ mem,
                           uint16_t* __restrict__ kv) {
    int t = blockIdx.x * blockDim.x + threadIdx.x;  // 0..65535
    int lane = t & 63;
    int fi = t >> 6;                                // 0..1023
    int f8 = fi & 7, mt = fi >> 3;
    size_t base = (size_t)mt * TILE_HW;
    {   // K fragment (hi/lo split)
        int m  = mt * 32 + (lane & 31);
        int d0 = f8 * 16 + (lane >> 5) * 8;
        const float* src = mem + (size_t)m * D_DIM + d0;
        #pragma unroll
        for (int e = 0; e < 8; ++e) {
            float x = src[e];
            uint16_t hb = f32_to_bf16_rne(x);
            kv[base + f8 * 512 + lane * 8 + e] = hb;
            kv[base + 4096 + f8 * 512 + lane * 8 + e] =
                f32_to_bf16_rne(x - bf16_to_f32(hb));
        }
    }
    {   // V^T fragment (plain bf16)
        int dt = fi & 3, ks = (fi >> 2) & 1;
        int d  = dt * 32 + (lane & 31);
        int m0 = mt * 32 + ks * 16 + (lane >> 5) * 8;
        #pragma unroll
        for (int e = 0; e < 8; ++e)
            kv[base + 8192 + f8 * 512 + lane * 8 + e] =
                f32_to_bf16_rne(mem[(size_t)(m0 + e) * D_DIM + d]);
    }
}

// ---------------------------------------------------------------------------
// Main kernel: 512 blocks x 256 threads (4 waves). Block bx: q-chunk bx>>1,
// memory half bx&1 (64 tiles). LDS double-buffered 24KB tiles (48 KB).
// ---------------------------------------------------------------------------

#define STAGE(t_, wb_) do {                                                   \
    const char* g_ = (const char*)(kv + (size_t)(tilebase + (t_)) * TILE_HW); \
    char* l_ = (char*)&sbuf[wb_][0];                                          \
    _Pragma("unroll")                                                         \
    for (int j_ = 0; j_ < 6; ++j_) {                                          \
        int ch_ = wave * 6 + j_;                                              \
        __builtin_amdgcn_global_load_lds(                                     \
            (const AS1 char*)(g_ + ch_ * 1024 + lane * 16),                   \
            (AS3 char*)(l_ + ch_ * 1024), 16, 0, 0);                          \
    }                                                                         \
} while (0)

#define MFMA_BF16(a_, b_, c_) __builtin_amdgcn_mfma_f32_32x32x16_bf16(a_, b_, c_, 0, 0, 0)

#define PSTORE_TILE(Ot_, t_) do {                                             \
    _Pragma("unroll")                                                         \
    for (int g_ = 0; g_ < 4; ++g_) {                                          \
        float4 v_ = { Ot_[4*g_+0], Ot_[4*g_+1], Ot_[4*g_+2], Ot_[4*g_+3] };   \
        int d_ = (t_) * 32 + 8 * g_ + 4 * hi32;                               \
        *(float4*)(prow + d_) = v_;                                           \
    }                                                                         \
} while (0)

__global__ __launch_bounds__(256, 2)
void attn_main(const float* __restrict__ qin,
               const uint16_t* __restrict__ kv,
               float* __restrict__ pout,      // [2][B_ROWS][128] partial O
               float2* __restrict__ pml) {    // [2][B_ROWS] (m, l)
    __shared__ uint16_t sbuf[2][TILE_HW];   // 2 x 24 KB

    const int lane = threadIdx.x & 63;
    const int wave = threadIdx.x >> 6;
    const int half = blockIdx.x & 1;
    const int tilebase = half * HALF_TILES;
    const int q0   = (blockIdx.x >> 1) * 128 + wave * 32;
    const int qrow = q0 + (lane & 31);
    const int hi32 = lane >> 5;

    // Q prep: scale by log2(e), split into bf16 hi/lo (B-frag of Sᵀ MFMA).
    bf16x8 qhi[8], qlo[8];
    {
        const float LOG2E = 1.44269504088896340736f;
        #pragma unroll
        for (int kk = 0; kk < 8; ++kk) {
            const float* src = qin + (size_t)qrow * D_DIM + kk * 16 + hi32 * 8;
            float4 a = *(const float4*)(src);
            float4 b = *(const float4*)(src + 4);
            float xs[8] = {a.x, a.y, a.z, a.w, b.x, b.y, b.z, b.w};
            #pragma unroll
            for (int e = 0; e < 8; ++e) {
                float x = xs[e] * LOG2E;
                uint16_t hb = f32_to_bf16_rne(x);
                qhi[kk][e] = (short)hb;
                qlo[kk][e] = (short)f32_to_bf16_rne(x - bf16_to_f32(hb));
            }
        }
    }

    f32x16 O0, O1, O2, O3;
    #pragma unroll
    for (int i = 0; i < 16; ++i) { O0[i]=0.f; O1[i]=0.f; O2[i]=0.f; O3[i]=0.f; }
    float m_run = -1e30f, l_run = 0.f;

    STAGE(0, 0);
    __syncthreads();

    #pragma unroll 1
    for (int t = 0; t < HALF_TILES; ++t) {
        const int rb = t & 1;
        if (t + 1 < HALF_TILES) STAGE(t + 1, rb ^ 1);
        const uint16_t* bp = &sbuf[rb][0] + lane * 8;

        // ---- QK^T: bf16x3 split, 2 accumulator chains (hi and merged-lo) ----
        f32x16 sh, sl;
        #pragma unroll
        for (int i = 0; i < 16; ++i) { sh[i] = 0.f; sl[i] = 0.f; }
        #pragma unroll
        for (int kk = 0; kk < 8; ++kk) {
            bf16x8 kh = *(const bf16x8*)(bp + kk * 512);
            bf16x8 kl = *(const bf16x8*)(bp + 4096 + kk * 512);
            sh = MFMA_BF16(kh, qhi[kk], sh);
            sl = MFMA_BF16(kh, qlo[kk], sl);
            sl = MFMA_BF16(kl, qhi[kk], sl);
        }
        f32x16 s = sh + sl;   // Sᵀ[m][q], log2-domain logits

        // ---- online softmax (q = lane&31; pair lane lane^32 has other 16 m) ----
        {
            float a0=fmaxf(s[0],s[1]),  a1=fmaxf(s[2],s[3]);
            float a2=fmaxf(s[4],s[5]),  a3=fmaxf(s[6],s[7]);
            float a4=fmaxf(s[8],s[9]),  a5=fmaxf(s[10],s[11]);
            float a6=fmaxf(s[12],s[13]),a7=fmaxf(s[14],s[15]);
            float tmax = fmaxf(fmaxf(fmaxf(a0,a1),fmaxf(a2,a3)),
                               fmaxf(fmaxf(a4,a5),fmaxf(a6,a7)));
            tmax = fmaxf(tmax, __shfl_xor(tmax, 32));
            if (__any(tmax > m_run + 8.0f)) {     // defer-max (T13)
                float mn = fmaxf(m_run, tmax);
                float fr = EXP2F(m_run - mn);
                m_run = mn; l_run *= fr;
                #pragma unroll
                for (int r = 0; r < 16; ++r) {
                    O0[r] *= fr; O1[r] *= fr; O2[r] *= fr; O3[r] *= fr;
                }
            }
        }
        #pragma unroll
        for (int r = 0; r < 16; ++r) s[r] = EXP2F(s[r] - m_run);
        {
            float q0s=s[0]+s[1],  q1s=s[2]+s[3],  q2s=s[4]+s[5],  q3s=s[6]+s[7];
            float q4s=s[8]+s[9],  q5s=s[10]+s[11],q6s=s[12]+s[13],q7s=s[14]+s[15];
            l_run += ((q0s+q1s)+(q2s+q3s)) + ((q4s+q5s)+(q6s+q7s));
        }

        // ---- P(f32) -> bf16 B-frags via cvt_pk + permlane32_swap (T12) ----
        u32 c_[8];
        #pragma unroll
        for (int j = 0; j < 8; ++j)
            asm("v_cvt_pk_bf16_f32 %0, %1, %2"
                : "=v"(c_[j]) : "v"(s[2*j]), "v"(s[2*j+1]));
        asm("v_permlane32_swap_b32 %0, %1" : "+v"(c_[0]), "+v"(c_[2]));
        asm("v_permlane32_swap_b32 %0, %1" : "+v"(c_[1]), "+v"(c_[3]));
        asm("v_permlane32_swap_b32 %0, %1" : "+v"(c_[4]), "+v"(c_[6]));
        asm("v_permlane32_swap_b32 %0, %1" : "+v"(c_[5]), "+v"(c_[7]));
        bf16x8 pf0, pf1;
        { u32 w[4] = {c_[0], c_[1], c_[2], c_[3]}; __builtin_memcpy(&pf0, w, 16); }
        { u32 w[4] = {c_[4], c_[5], c_[6], c_[7]}; __builtin_memcpy(&pf1, w, 16); }

        // ---- PV: Oᵀ[d][q] += Vᵀ·Pᵀ, V fragments streamed from LDS ----
        {
            bf16x8 vf;
            vf = *(const bf16x8*)(bp + 8192 + 0*512); O0 = MFMA_BF16(vf, pf0, O0);
            vf = *(const bf16x8*)(bp + 8192 + 1*512); O1 = MFMA_BF16(vf, pf0, O1);
            vf = *(const bf16x8*)(bp + 8192 + 2*512); O2 = MFMA_BF16(vf, pf0, O2);
            vf = *(const bf16x8*)(bp + 8192 + 3*512); O3 = MFMA_BF16(vf, pf0, O3);
            vf = *(const bf16x8*)(bp + 8192 + 4*512); O0 = MFMA_BF16(vf, pf1, O0);
            vf = *(const bf16x8*)(bp + 8192 + 5*512); O1 = MFMA_BF16(vf, pf1, O1);
            vf = *(const bf16x8*)(bp + 8192 + 6*512); O2 = MFMA_BF16(vf, pf1, O2);
            vf = *(const bf16x8*)(bp + 8192 + 7*512); O3 = MFMA_BF16(vf, pf1, O3);
        }
        __syncthreads();
    }

    // ---- partial store (un-normalized O, plus m,l) ----
    l_run += __shfl_xor(l_run, 32);     // pair-lane partial sums
    float* prow = pout + ((size_t)half * B_ROWS + qrow) * D_DIM;
    PSTORE_TILE(O0, 0); PSTORE_TILE(O1, 1);
    PSTORE_TILE(O2, 2); PSTORE_TILE(O3, 3);
    if (lane < 32) {
        pml[(size_t)half * B_ROWS + qrow] = make_float2(m_run, l_run);
    }
}

// ---------------------------------------------------------------------------
// Merge: out = (P0*w0 + P1*w1) / (l0*w0 + l1*w1), w_i = exp2(m_i - max).
// One float4 per thread: 32768*32 float4s / 256 = 4096 blocks.
// ---------------------------------------------------------------------------
__global__ __launch_bounds__(256)
void merge_halves(const float* __restrict__ pout,
                  const float2* __restrict__ pml,
                  float* __restrict__ out) {
    int idx  = blockIdx.x * 256 + threadIdx.x;   // 0 .. 2^20-1
    int row  = idx >> 5;
    int c4   = idx & 31;
    float2 a = pml[row];
    float2 b = pml[B_ROWS + row];
    float mn = fmaxf(a.x, b.x);
    float wa = EXP2F(a.x - mn);
    float wb = EXP2F(b.x - mn);
    float rinv = 1.0f / (a.y * wa + b.y * wb);
    const float4* P0 = (const float4*)(pout + (size_t)row * D_DIM) + c4;
    const float4* P1 = (const float4*)(pout + ((size_t)B_ROWS + row) * D_DIM) + c4;
    float4 p0 = *P0, p1 = *P1;
    float4 v;
    v.x = (p0.x * wa + p1.x * wb) * rinv;
    v.y = (p0.y * wa + p1.y * wb) * rinv;
    v.z = (p0.z * wa + p1.z * wb) * rinv;
    v.w = (p0.w * wa + p1.w * wb) * rinv;
    *((float4*)(out + (size_t)row * D_DIM) + c4) = v;
}

extern "C" void kernel_launch(void* const* d_in, const int* in_sizes, int n_in,
                              void* d_out, int out_size, void* d_ws, size_t ws_size,
                              hipStream_t stream) {
    const float* local_stats = (const float*)d_in[0];   // [32768,128] f32
    const float* memory      = (const float*)d_in[1];   // [4096,128]  f32
    float* out = (float*)d_out;                         // [32768,128] f32

    // ws layout: kv frags 3MB | partial O 32MB | partial (m,l) 0.5MB
    uint16_t* kv  = (uint16_t*)d_ws;
    float*   pout = (float*)((char*)d_ws + 3 * 1024 * 1024);
    float2*  pml  = (float2*)((char*)pout + (size_t)2 * B_ROWS * D_DIM * 4);

    prep_frags<<<256, 256, 0, stream>>>(memory, kv);
    attn_main<<<512, 256, 0, stream>>>(local_stats, kv, pout, pml);
    merge_halves<<<4096, 256, 0, stream>>>(pout, pml, out);
}